// Round 10
// baseline (73.678 us; speedup 1.0000x reference)
//
#include <hip/hip_runtime.h>

#define NB 4
#define NCI 64
#define NCO 64
#define NH 256
#define NW 256
#define NIMG (NB*NCI)      // 256
#define PLANE (NIMG*NH)    // 65536

// workspace offsets (in floats)
#define OF_COS 0
#define OF_SIN 256
#define OF_TW  512                      // [30][256] final-stage trig (ky=1..15 cos/sin)
#define OF_XW  16384                    // Xw: [img][32 planes][256 rows]
#define OF_XS_RE (OF_XW + 32*PLANE)
#define OF_XS_IM (OF_XS_RE + PLANE)
#define OF_O1_RE (OF_XS_IM + PLANE)
#define OF_O1_IM (OF_O1_RE + PLANE)
#define OF_O2_RE (OF_O1_IM + PLANE)
#define OF_O2_IM (OF_O2_RE + PLANE)

// k1 LDS plane layout: 128-row planes, pad 132; xo planes at +8 bank stagger
#define PL 132
#define XE(w) ((w)*PL)
#define XO(w) (16*PL + 8 + (w)*PL)

// grid 31: block 0 -> cos/sin tables; blocks 1..30 -> one TW row each
__global__ __launch_bounds__(256) void k0_init(float* __restrict__ ws) {
  const int t = threadIdx.x, b = blockIdx.x;
  const double TP = 6.283185307179586;
  if (b == 0) {
    double a = TP * t / 256.0;
    ws[OF_COS + t] = (float)cos(a);
    ws[OF_SIN + t] = (float)sin(a);
  } else {
    const int p = b - 1;              // 0..29
    const int ky = (p >> 1) + 1;
    double a = TP * ((ky * t) & 255) / 256.0;
    ws[OF_TW + p*256 + t] = (p & 1) ? (float)sin(a) : (float)cos(a);
  }
}

// Stage 1: w-DFT, HALF image per block (grid 512 = 2 independent blocks/CU).
// Fold (w,w+128) at staging into xe/xo planes; parity-split ky map so each
// thread reads only its parity's plane; 4-way w-split merged via shfl_xor.
// Out: Xw[img][32 planes][256 rows] (planes: 16 Re ky, 16 Im ky).
__global__ __launch_bounds__(512, 4) void k1_dftw(const float* __restrict__ x,
                                                  float* __restrict__ ws) {
  __shared__ float buf[32*PL + 8];     // 16 xe + 16 xo planes of 128 rows
  __shared__ float cst[256], snt[256];
  const int t = threadIdx.x;
  const int img  = blockIdx.x >> 1;
  const int half = blockIdx.x & 1;

  if (t < 256) { cst[t] = ws[OF_COS + t]; snt[t] = ws[OF_SIN + t]; }

  const int sl = t & 3, row = t >> 2;            // staging: 4 slots x 128 rows
  const int wq = t & 3, p = (t >> 2) & 1;        // compute map
  const int kg = (t >> 3) & 1, tr = t >> 4;      // tr 0..31
  int kyv[4];
#pragma unroll
  for (int j = 0; j < 4; ++j) kyv[j] = p + 8*kg + 2*j;

  const float* xb = x + (size_t)img * 65536 + (size_t)(half*128) * 256;
  float4 lo = *(const float4*)(xb + row*256 + sl*4);
  float4 hi = *(const float4*)(xb + row*256 + 128 + sl*4);

  __syncthreads();                     // cst/snt ready

  float cd[4], sd[4];
#pragma unroll
  for (int j = 0; j < 4; ++j) { cd[j] = cst[kyv[j]]; sd[j] = snt[kyv[j]]; }

  float ar[4][4], ai[4][4];            // [j][row-quad]
#pragma unroll
  for (int j = 0; j < 4; ++j)
#pragma unroll
    for (int r = 0; r < 4; ++r) { ar[j][r] = 0.f; ai[j][r] = 0.f; }

  const int pbase = p ? (16*PL + 8) : 0;

  for (int c = 0; c < 8; ++c) {
    __syncthreads();                   // prev chunk compute done
    buf[XE(sl*4+0) + row] = lo.x + hi.x;
    buf[XE(sl*4+1) + row] = lo.y + hi.y;
    buf[XE(sl*4+2) + row] = lo.z + hi.z;
    buf[XE(sl*4+3) + row] = lo.w + hi.w;
    buf[XO(sl*4+0) + row] = lo.x - hi.x;
    buf[XO(sl*4+1) + row] = lo.y - hi.y;
    buf[XO(sl*4+2) + row] = lo.z - hi.z;
    buf[XO(sl*4+3) + row] = lo.w - hi.w;
    __syncthreads();
    if (c < 7) {                       // T14: prefetch next chunk
      const int w0n = (c+1) * 16;
      lo = *(const float4*)(xb + row*256 + w0n + sl*4);
      hi = *(const float4*)(xb + row*256 + w0n + 128 + sl*4);
    }
    float cc[4], sv[4];
#pragma unroll
    for (int j = 0; j < 4; ++j) {
      const int m = (kyv[j] * (c*16 + wq*4)) & 255;
      cc[j] = cst[m];
      sv[j] = snt[m];
    }
#pragma unroll
    for (int i = 0; i < 4; ++i) {
      const int wl = wq*4 + i;
      const float4 xs4 = *(const float4*)&buf[pbase + wl*PL + tr*4];
#pragma unroll
      for (int j = 0; j < 4; ++j) {
        ar[j][0] += xs4.x * cc[j];  ai[j][0] -= xs4.x * sv[j];
        ar[j][1] += xs4.y * cc[j];  ai[j][1] -= xs4.y * sv[j];
        ar[j][2] += xs4.z * cc[j];  ai[j][2] -= xs4.z * sv[j];
        ar[j][3] += xs4.w * cc[j];  ai[j][3] -= xs4.w * sv[j];
        const float nc = cc[j]*cd[j] - sv[j]*sd[j];
        const float ns = sv[j]*cd[j] + cc[j]*sd[j];
        cc[j] = nc; sv[j] = ns;
      }
    }
  }

  // merge w-quarters (lane bits 0..1)
#pragma unroll
  for (int j = 0; j < 4; ++j)
#pragma unroll
    for (int r = 0; r < 4; ++r) {
      ar[j][r] += __shfl_xor(ar[j][r], 1);
      ar[j][r] += __shfl_xor(ar[j][r], 2);
      ai[j][r] += __shfl_xor(ai[j][r], 1);
      ai[j][r] += __shfl_xor(ai[j][r], 2);
    }
  if (wq == 0) {
    float* Xw = ws + OF_XW + (size_t)img * 8192 + half*128;
#pragma unroll
    for (int j = 0; j < 4; ++j) {
      const int ky = kyv[j];
      float4 sr; sr.x = ar[j][0]; sr.y = ar[j][1]; sr.z = ar[j][2]; sr.w = ar[j][3];
      float4 si; si.x = ai[j][0]; si.y = ai[j][1]; si.z = ai[j][2]; si.w = ai[j][3];
      *(float4*)&Xw[ky*256 + tr*4]      = sr;
      *(float4*)&Xw[(16+ky)*256 + tr*4] = si;
    }
  }
}

// Stage 2: xs[img][kx*16+ky] = sum_h Xw[img][.][h] * e^{-2pi i kx h/256}
// [R7-verbatim, measured ~5-6 us]
__global__ __launch_bounds__(256) void k2_dfth(float* __restrict__ ws) {
  __shared__ float L[32*257];   // [plane][h], pad 257
  const int t = threadIdx.x, img = blockIdx.x;
  const float* XwI = ws + OF_XW + (size_t)img * 8192;
  for (int p = 0; p < 32; ++p)
    L[p*257 + t] = XwI[p*256 + t];
  __syncthreads();
  const int kx = t >> 4, ky = t & 15;
  const float cdk = ws[OF_COS + kx];
  const float sdk = ws[OF_SIN + kx];
  float c = 1.f, s = 0.f, arr = 0.f, aii = 0.f;
#pragma unroll 4
  for (int h = 0; h < 256; ++h) {
    const float xr = L[ky*257 + h];
    const float xi = L[(16+ky)*257 + h];
    arr += xr*c + xi*s;
    aii += xi*c - xr*s;
    const float nc = c*cdk - s*sdk;
    const float ns = s*cdk + c*sdk;
    c = nc; s = ns;
  }
  ws[OF_XS_RE + img*256 + t] = arr;
  ws[OF_XS_IM + img*256 + t] = aii;
}

// Stage 3: o1/o2[b,o,m] = sum_i xs[b,i,m] * (wr + i wi)[i,o,m]
__global__ __launch_bounds__(256) void k3_mix(const float* __restrict__ w1r,
    const float* __restrict__ w1i, const float* __restrict__ w2r,
    const float* __restrict__ w2i, float* __restrict__ ws) {
  const int o  = blockIdx.x;     // 0..63
  const int mc = blockIdx.y;     // 0..3
  const int t  = threadIdx.x;    // 256
  const int b  = t >> 6;
  const int m  = (mc << 6) + (t & 63);
  const float* xsr = ws + OF_XS_RE;
  const float* xsi = ws + OF_XS_IM;
  float a1r=0.f, a1i=0.f, a2r=0.f, a2i=0.f;
#pragma unroll 4
  for (int i = 0; i < NCI; ++i) {
    const float xr = xsr[((b*NCI + i) << 8) + m];
    const float xi = xsi[((b*NCI + i) << 8) + m];
    const int wi = ((i*NCO + o) << 8) + m;
    const float p = w1r[wi], q = w1i[wi], u = w2r[wi], v = w2i[wi];
    a1r += xr*p - xi*q;
    a1i += xr*q + xi*p;
    a2r += xr*u - xi*v;
    a2i += xr*v + xi*u;
  }
  const int oi = ((b*NCO + o) << 8) + m;
  ws[OF_O1_RE + oi] = a1r;
  ws[OF_O1_IM + oi] = a1i;
  ws[OF_O2_RE + oi] = a2r;
  ws[OF_O2_IM + oi] = a2i;
}

// Fused stage 4+5 (R7-verbatim: grid 1024, best measured config).
__global__ __launch_bounds__(256) void k45_idft(const float* __restrict__ ws,
                                                float* __restrict__ out) {
  __shared__ __align__(16) float o1r[256], o1i[256], o2r[256], o2i[256];
  __shared__ float cst[256], snt[256];
  __shared__ __align__(16) float Sr[64][20], Si[64][20];
  const int t  = threadIdx.x;
  const int bo = blockIdx.x >> 2;
  const int hc = blockIdx.x & 3;

  o1r[t] = ws[OF_O1_RE + bo*256 + t];
  o1i[t] = ws[OF_O1_IM + bo*256 + t];
  o2r[t] = ws[OF_O2_RE + bo*256 + t];
  o2i[t] = ws[OF_O2_IM + bo*256 + t];
  cst[t] = ws[OF_COS + t];
  snt[t] = ws[OF_SIN + t];

  const int w0 = t & 63;
  const float* Tw = ws + OF_TW;
  float c[15], s[15];
#pragma unroll
  for (int k = 0; k < 15; ++k) {
    c[k] = Tw[(2*k)*256 + w0];
    s[k] = Tw[(2*k+1)*256 + w0];
  }
  __syncthreads();

  // ---- phase A ----
  {
    const int hl = t >> 2, kq = t & 3;
    const int h  = hc*64 + hl;
    const float chh = cst[h], shh = snt[h];
    float c1 = 1.f, s1 = 0.f;
    const int m2i = (240 * h) & 255;
    float c2 = cst[m2i], s2 = snt[m2i];
    float4 sr = {0.f,0.f,0.f,0.f}, si = {0.f,0.f,0.f,0.f};
    for (int j = 0; j < 16; ++j) {
      const float4 r1 = *(const float4*)&o1r[j*16 + kq*4];
      const float4 i1 = *(const float4*)&o1i[j*16 + kq*4];
      const float4 r2 = *(const float4*)&o2r[j*16 + kq*4];
      const float4 i2 = *(const float4*)&o2i[j*16 + kq*4];
      sr.x += r1.x*c1 - i1.x*s1 + r2.x*c2 - i2.x*s2;
      si.x += r1.x*s1 + i1.x*c1 + r2.x*s2 + i2.x*c2;
      sr.y += r1.y*c1 - i1.y*s1 + r2.y*c2 - i2.y*s2;
      si.y += r1.y*s1 + i1.y*c1 + r2.y*s2 + i2.y*c2;
      sr.z += r1.z*c1 - i1.z*s1 + r2.z*c2 - i2.z*s2;
      si.z += r1.z*s1 + i1.z*c1 + r2.z*s2 + i2.z*c2;
      sr.w += r1.w*c1 - i1.w*s1 + r2.w*c2 - i2.w*s2;
      si.w += r1.w*s1 + i1.w*c1 + r2.w*s2 + i2.w*c2;
      const float n1c = c1*chh - s1*shh, n1s = s1*chh + c1*shh;
      const float n2c = c2*chh - s2*shh, n2s = s2*chh + c2*shh;
      c1 = n1c; s1 = n1s; c2 = n2c; s2 = n2s;
    }
    *(float4*)&Sr[hl][kq*4] = sr;
    *(float4*)&Si[hl][kq*4] = si;
  }
  __syncthreads();

  // ---- phase B: radix-4 butterfly over ky mod 4 ----
  const int rg = t >> 6;
  const float scale = 2.0f / 65536.0f;
  const size_t rowbase = ((size_t)bo*256 + hc*64 + rg*16) * 256;
#pragma unroll 2
  for (int r = 0; r < 16; ++r) {
    const int hl = rg*16 + r;
    const float4 a0 = *(const float4*)&Sr[hl][0];
    const float4 a1 = *(const float4*)&Sr[hl][4];
    const float4 a2 = *(const float4*)&Sr[hl][8];
    const float4 a3 = *(const float4*)&Sr[hl][12];
    const float4 b0 = *(const float4*)&Si[hl][0];
    const float4 b1 = *(const float4*)&Si[hl][4];
    const float4 b2 = *(const float4*)&Si[hl][8];
    const float4 b3 = *(const float4*)&Si[hl][12];

    float PA = 0.5f * a0.x;
    float PB = 0.f, PC = 0.f, PD = 0.f, QB = 0.f, QD = 0.f;
    PB += a0.y*c[0] - b0.y*s[0];   QB += a0.y*s[0] + b0.y*c[0];
    PC += a0.z*c[1] - b0.z*s[1];
    PD += a0.w*c[2] - b0.w*s[2];   QD += a0.w*s[2] + b0.w*c[2];
    PA += a1.x*c[3] - b1.x*s[3];
    PB += a1.y*c[4] - b1.y*s[4];   QB += a1.y*s[4] + b1.y*c[4];
    PC += a1.z*c[5] - b1.z*s[5];
    PD += a1.w*c[6] - b1.w*s[6];   QD += a1.w*s[6] + b1.w*c[6];
    PA += a2.x*c[7] - b2.x*s[7];
    PB += a2.y*c[8] - b2.y*s[8];   QB += a2.y*s[8] + b2.y*c[8];
    PC += a2.z*c[9] - b2.z*s[9];
    PD += a2.w*c[10] - b2.w*s[10]; QD += a2.w*s[10] + b2.w*c[10];
    PA += a3.x*c[11] - b3.x*s[11];
    PB += a3.y*c[12] - b3.y*s[12]; QB += a3.y*s[12] + b3.y*c[12];
    PC += a3.z*c[13] - b3.z*s[13];
    PD += a3.w*c[14] - b3.w*s[14]; QD += a3.w*s[14] + b3.w*c[14];

    const float T1 = PA + PC, T2 = PB + PD;
    const float T3 = PA - PC, T4 = QB - QD;
    const size_t ob = rowbase + (size_t)r*256 + w0;
    out[ob]       = (T1 + T2) * scale;
    out[ob + 64]  = (T3 - T4) * scale;
    out[ob + 128] = (T1 - T2) * scale;
    out[ob + 192] = (T3 + T4) * scale;
  }
}

extern "C" void kernel_launch(void* const* d_in, const int* in_sizes, int n_in,
                              void* d_out, int out_size, void* d_ws, size_t ws_size,
                              hipStream_t stream) {
  const float* x   = (const float*)d_in[0];
  const float* w1r = (const float*)d_in[1];
  const float* w1i = (const float*)d_in[2];
  const float* w2r = (const float*)d_in[3];
  const float* w2i = (const float*)d_in[4];
  float* out = (float*)d_out;
  float* ws  = (float*)d_ws;

  hipLaunchKernelGGL(k0_init,  dim3(31),    dim3(256), 0, stream, ws);
  hipLaunchKernelGGL(k1_dftw,  dim3(512),   dim3(512), 0, stream, x, ws);
  hipLaunchKernelGGL(k2_dfth,  dim3(256),   dim3(256), 0, stream, ws);
  hipLaunchKernelGGL(k3_mix,   dim3(64, 4), dim3(256), 0, stream, w1r, w1i, w2r, w2i, ws);
  hipLaunchKernelGGL(k45_idft, dim3(1024),  dim3(256), 0, stream, ws, out);
}